// Round 1
// baseline (50.889 us; speedup 1.0000x reference)
//
#include <hip/hip_runtime.h>

#define IN_CH 32
#define OUT_CH 32
#define M1 16
#define M2 16
#define B_ 8
#define L_ 16
#define H_ 64
#define W_ 33
#define BL (B_*L_)      // 128
#define HW (H_*W_)      // 2112

// One block per (bl, region, i): 128 * 2 * 16 = 4096 blocks, 256 threads.
// Each block:
//   - stages x[bl, 0..31, h, 0..15] (512 complex) into LDS
//   - zeroes its 1/32 share of the middle band h in [16,48) (float4)
//   - zeroes the w in [16,33) tail of its 32 output rows (float2)
//   - computes out[bl, o, h, j] for o in [0,32), j in [0,16): 2 outputs/thread
__global__ __launch_bounds__(256) void spectral_kernel(
    const float* __restrict__ x_re, const float* __restrict__ x_im,
    const float* __restrict__ w1_re, const float* __restrict__ w1_im,
    const float* __restrict__ w2_re, const float* __restrict__ w2_im,
    float* __restrict__ out)
{
    const int tid = threadIdx.x;
    const int blk = blockIdx.x;          // [0, 4096)
    const int bl  = blk >> 5;            // [0, 128)
    const int ri  = blk & 31;            // region*16 + i
    const int region = ri >> 4;
    const int i   = ri & 15;
    const int h   = region ? (H_ - M1 + i) : i;

    __shared__ float2 xs[IN_CH][M2];

    // ---- stage x[bl, c, h, 0..15] into LDS (this slice is unique to this block) ----
    {
        int item = tid;                  // item = c*16 + j
        #pragma unroll
        for (int rep = 0; rep < 2; ++rep) {
            int c = item >> 4, j = item & 15;
            long src = (long)(bl * IN_CH + c) * HW + (long)h * W_ + j;
            xs[c][j] = make_float2(x_re[src], x_im[src]);
            item += 256;
        }
    }

    // ---- zero this block's share of the middle band: o = ri, h in [16,48), all w ----
    {
        float4* out4 = (float4*)out;
        // float4 base for (bl, o=ri), h=16..47: ((bl*32+o)*64 + 16)*66 floats / 4
        const long base4 = (long)bl * 33792 + (long)ri * 1056 + 264;   // 528 float4s
        const float4 z = make_float4(0.f, 0.f, 0.f, 0.f);
        out4[base4 + tid]       = z;
        out4[base4 + tid + 256] = z;
        if (tid < 16) out4[base4 + tid + 512] = z;
    }

    // ---- zero tail w in [16,33) for this block's 32 rows (all o, this h) ----
    {
        float2* out2 = (float2*)out;
        for (int idx = tid; idx < 32 * 17; idx += 256) {
            int o  = idx / 17;
            int wq = idx % 17 + 16;
            long dst = ((long)(bl * OUT_CH + o) * H_ + h) * W_ + wq;   // float2 units
            out2[dst] = make_float2(0.f, 0.f);
        }
    }

    __syncthreads();

    // ---- compute: thread (j, o0) does outputs o0 and o0+16 ----
    const int j  = tid & 15;
    const int o0 = tid >> 4;             // [0, 16)
    const int o1 = o0 + 16;
    const float* __restrict__ wre = region ? w2_re : w1_re;
    const float* __restrict__ wim = region ? w2_im : w1_im;

    float ar0 = 0.f, ai0 = 0.f, ar1 = 0.f, ai1 = 0.f;
    // w index: ((c*32 + o)*16 + i)*16 + j
    const int wbase0 = (o0 * M1 + i) * M2 + j;
    const int wbase1 = (o1 * M1 + i) * M2 + j;
    #pragma unroll 8
    for (int c = 0; c < IN_CH; ++c) {
        float2 xc = xs[c][j];
        int idx0 = wbase0 + c * (OUT_CH * M1 * M2);
        int idx1 = wbase1 + c * (OUT_CH * M1 * M2);
        float wr0 = wre[idx0], wi0 = wim[idx0];
        float wr1 = wre[idx1], wi1 = wim[idx1];
        ar0 = fmaf(xc.x, wr0, ar0); ar0 = fmaf(-xc.y, wi0, ar0);
        ai0 = fmaf(xc.x, wi0, ai0); ai0 = fmaf( xc.y, wr0, ai0);
        ar1 = fmaf(xc.x, wr1, ar1); ar1 = fmaf(-xc.y, wi1, ar1);
        ai1 = fmaf(xc.x, wi1, ai1); ai1 = fmaf( xc.y, wr1, ai1);
    }

    float2* out2 = (float2*)out;
    long dst0 = ((long)(bl * OUT_CH + o0) * H_ + h) * W_ + j;
    long dst1 = ((long)(bl * OUT_CH + o1) * H_ + h) * W_ + j;
    out2[dst0] = make_float2(ar0, ai0);
    out2[dst1] = make_float2(ar1, ai1);
}

extern "C" void kernel_launch(void* const* d_in, const int* in_sizes, int n_in,
                              void* d_out, int out_size, void* d_ws, size_t ws_size,
                              hipStream_t stream) {
    const float* x_re  = (const float*)d_in[0];
    const float* x_im  = (const float*)d_in[1];
    const float* w1_re = (const float*)d_in[2];
    const float* w1_im = (const float*)d_in[3];
    const float* w2_re = (const float*)d_in[4];
    const float* w2_im = (const float*)d_in[5];
    float* out = (float*)d_out;

    spectral_kernel<<<dim3(4096), dim3(256), 0, stream>>>(
        x_re, x_im, w1_re, w1_im, w2_re, w2_im, out);
}

// Round 2
// 40.046 us; speedup vs baseline: 1.2708x; 1.2708x over previous
//
#include <hip/hip_runtime.h>

#define IN_CH 32
#define OUT_CH 32
#define M1 16
#define M2 16
#define H_ 64
#define W_ 33
#define HW (H_*W_)          // 2112
#define BLPB 8              // batch-l elements per block
#define WSTRIDE (OUT_CH*M1*M2)  // 8192 floats per c step in w

// ---------------- Kernel 1: zero the complement of the computed region ----------------
// Part A: middle band h in [16,48), all w  -> 4096 planes x 528 float4 (34.6 MB)
// Part B: w in [16,33) tails of h in [0,16) u [48,64) -> 4096 planes x 32 rows x 17 float2 (17.8 MB)
__global__ __launch_bounds__(256) void fill_zero(float* __restrict__ out) {
    const int tid = blockIdx.x * 256 + threadIdx.x;
    const int nthreads = gridDim.x * 256;

    float4* out4 = (float4*)out;
    const float4 z4 = make_float4(0.f, 0.f, 0.f, 0.f);
    const int totalA = 4096 * 528;
    for (int idx = tid; idx < totalA; idx += nthreads) {
        int plane = idx / 528;
        int k = idx - plane * 528;
        out4[(long)plane * 1056 + 264 + k] = z4;   // plane=4224 floats=1056 f4; h=16 -> 264 f4
    }

    float2* out2 = (float2*)out;
    const float2 z2 = make_float2(0.f, 0.f);
    const int totalB = 4096 * 32 * 17;
    for (int idx = tid; idx < totalB; idx += nthreads) {
        int plane = idx / 544;
        int r = idx - plane * 544;
        int hh = r / 17;
        int t = r - hh * 17;
        int h = hh < 16 ? hh : hh + 32;            // [0,16) u [48,64)
        out2[(long)plane * 2112 + h * 33 + 16 + t] = z2;
    }
}

// ---------------- Kernel 2: compute the two mode regions ----------------
// Grid: (region*16 + i) * 16 chunks = 512 blocks, 256 threads.
// Block handles 8 bl values for one (region, i): weight slice read once per block,
// 64 FMAs per 4 global weight loads per c-iteration.
__global__ __launch_bounds__(256) void spectral_compute(
    const float* __restrict__ x_re, const float* __restrict__ x_im,
    const float* __restrict__ w1_re, const float* __restrict__ w1_im,
    const float* __restrict__ w2_re, const float* __restrict__ w2_im,
    float* __restrict__ out)
{
    const int tid = threadIdx.x;
    const int blk = blockIdx.x;           // [0, 512)
    const int chunk = blk & 15;           // 16 chunks of 8 bl
    const int ri = blk >> 4;              // region*16 + i
    const int region = ri >> 4;
    const int i = ri & 15;
    const int h = region ? (48 + i) : i;
    const int bl0 = chunk * BLPB;

    __shared__ float2 xs[BLPB][IN_CH][M2];   // 32 KB

    // stage x[bl0..bl0+7, all c, h, 0..15]; 4096 float2, 16 per thread, j-fastest (coalesced 64B)
    for (int item = tid; item < BLPB * IN_CH * M2; item += 256) {
        int j = item & 15;
        int c = (item >> 4) & 31;
        int b = item >> 9;
        long src = (long)((bl0 + b) * IN_CH + c) * HW + (long)h * W_ + j;
        xs[b][c][j] = make_float2(x_re[src], x_im[src]);
    }
    __syncthreads();

    const int j  = tid & 15;
    const int o0 = tid >> 4;              // [0,16); also handles o0+16
    const float* __restrict__ wre = region ? w2_re : w1_re;
    const float* __restrict__ wim = region ? w2_im : w1_im;

    float2 acc0[BLPB], acc1[BLPB];
    #pragma unroll
    for (int b = 0; b < BLPB; ++b) {
        acc0[b] = make_float2(0.f, 0.f);
        acc1[b] = make_float2(0.f, 0.f);
    }

    const int wbase = (o0 * M1 + i) * M2 + j;     // (o0+16) is wbase + 4096
    #pragma unroll 4
    for (int c = 0; c < IN_CH; ++c) {
        int idx = wbase + c * WSTRIDE;
        float wr0 = wre[idx],        wi0 = wim[idx];
        float wr1 = wre[idx + 4096], wi1 = wim[idx + 4096];
        #pragma unroll
        for (int b = 0; b < BLPB; ++b) {
            float2 xc = xs[b][c][j];
            acc0[b].x = fmaf(xc.x, wr0, acc0[b].x); acc0[b].x = fmaf(-xc.y, wi0, acc0[b].x);
            acc0[b].y = fmaf(xc.x, wi0, acc0[b].y); acc0[b].y = fmaf( xc.y, wr0, acc0[b].y);
            acc1[b].x = fmaf(xc.x, wr1, acc1[b].x); acc1[b].x = fmaf(-xc.y, wi1, acc1[b].x);
            acc1[b].y = fmaf(xc.x, wi1, acc1[b].y); acc1[b].y = fmaf( xc.y, wr1, acc1[b].y);
        }
    }

    float2* out2 = (float2*)out;
    #pragma unroll
    for (int b = 0; b < BLPB; ++b) {
        long plane = (long)(bl0 + b) * OUT_CH;
        long d0 = (plane + o0)      * HW + (long)h * W_ + j;
        long d1 = (plane + o0 + 16) * HW + (long)h * W_ + j;
        out2[d0] = acc0[b];
        out2[d1] = acc1[b];
    }
}

extern "C" void kernel_launch(void* const* d_in, const int* in_sizes, int n_in,
                              void* d_out, int out_size, void* d_ws, size_t ws_size,
                              hipStream_t stream) {
    const float* x_re  = (const float*)d_in[0];
    const float* x_im  = (const float*)d_in[1];
    const float* w1_re = (const float*)d_in[2];
    const float* w1_im = (const float*)d_in[3];
    const float* w2_re = (const float*)d_in[4];
    const float* w2_im = (const float*)d_in[5];
    float* out = (float*)d_out;

    fill_zero<<<dim3(2048), dim3(256), 0, stream>>>(out);
    spectral_compute<<<dim3(512), dim3(256), 0, stream>>>(
        x_re, x_im, w1_re, w1_im, w2_re, w2_im, out);
}

// Round 3
// 37.833 us; speedup vs baseline: 1.3451x; 1.0585x over previous
//
#include <hip/hip_runtime.h>

#define IN_CH 32
#define OUT_CH 32
#define M1 16
#define M2 16
#define H_ 64
#define W_ 33
#define HW (H_*W_)          // 2112
#define BLPB 4              // batch-l elements per compute block
#define WSTRIDE (OUT_CH*M1*M2)  // 8192 floats per c step in w

// Single kernel, 2048 blocks x 256 threads.
//   even blocks (1024): compute the two mode regions (BLPB bl per block)
//   odd blocks  (1024): zero-fill the complement (pure write stream)
// Fill overlaps compute's L2-latency stalls -> HBM write BW stays saturated.
__global__ __launch_bounds__(256) void spectral_fused(
    const float* __restrict__ x_re, const float* __restrict__ x_im,
    const float* __restrict__ w1_re, const float* __restrict__ w1_im,
    const float* __restrict__ w2_re, const float* __restrict__ w2_im,
    float* __restrict__ out)
{
    const int tid = threadIdx.x;

    if (blockIdx.x & 1) {
        // ---------------- fill role ----------------
        const int fid = blockIdx.x >> 1;          // [0, 1024)
        const int gtid = fid * 256 + tid;
        const int nthreads = 1024 * 256;

        // Part A: middle band h in [16,48), all w: 4096 planes x 528 float4
        float4* out4 = (float4*)out;
        const float4 z4 = make_float4(0.f, 0.f, 0.f, 0.f);
        const int totalA = 4096 * 528;
        for (int idx = gtid; idx < totalA; idx += nthreads) {
            int plane = idx / 528;
            int k = idx - plane * 528;
            out4[(long)plane * 1056 + 264 + k] = z4;
        }
        // Part B: w in [16,33) tails of the two corner bands: 4096 planes x 32 rows x 17 float2
        float2* out2 = (float2*)out;
        const float2 z2 = make_float2(0.f, 0.f);
        const int totalB = 4096 * 544;
        for (int idx = gtid; idx < totalB; idx += nthreads) {
            int plane = idx / 544;
            int r = idx - plane * 544;
            int hh = r / 17;
            int t = r - hh * 17;
            int h = hh < 16 ? hh : hh + 32;
            out2[(long)plane * 2112 + h * 33 + 16 + t] = z2;
        }
        return;
    }

    // ---------------- compute role ----------------
    const int cid = blockIdx.x >> 1;      // [0, 1024)
    const int ri = cid >> 5;              // region*16 + i
    const int chunk = cid & 31;           // 32 chunks of BLPB bl
    const int region = ri >> 4;
    const int i = ri & 15;
    const int h = region ? (48 + i) : i;
    const int bl0 = chunk * BLPB;

    __shared__ float2 xs[BLPB][IN_CH][M2];   // 16 KB

    for (int item = tid; item < BLPB * IN_CH * M2; item += 256) {
        int j = item & 15;
        int c = (item >> 4) & 31;
        int b = item >> 9;
        long src = (long)((bl0 + b) * IN_CH + c) * HW + (long)h * W_ + j;
        xs[b][c][j] = make_float2(x_re[src], x_im[src]);
    }
    __syncthreads();

    const int j  = tid & 15;
    const int o0 = tid >> 4;              // [0,16); also handles o0+16
    const float* __restrict__ wre = (region ? w2_re : w1_re) + (o0 * M1 + i) * M2 + j;
    const float* __restrict__ wim = (region ? w2_im : w1_im) + (o0 * M1 + i) * M2 + j;

    float2 acc0[BLPB], acc1[BLPB];
    #pragma unroll
    for (int b = 0; b < BLPB; ++b) {
        acc0[b] = make_float2(0.f, 0.f);
        acc1[b] = make_float2(0.f, 0.f);
    }

    #pragma unroll 8
    for (int c = 0; c < IN_CH; ++c) {
        int idx = c * WSTRIDE;
        float wr0 = wre[idx],        wi0 = wim[idx];
        float wr1 = wre[idx + 4096], wi1 = wim[idx + 4096];
        #pragma unroll
        for (int b = 0; b < BLPB; ++b) {
            float2 xc = xs[b][c][j];
            acc0[b].x = fmaf(xc.x, wr0, acc0[b].x); acc0[b].x = fmaf(-xc.y, wi0, acc0[b].x);
            acc0[b].y = fmaf(xc.x, wi0, acc0[b].y); acc0[b].y = fmaf( xc.y, wr0, acc0[b].y);
            acc1[b].x = fmaf(xc.x, wr1, acc1[b].x); acc1[b].x = fmaf(-xc.y, wi1, acc1[b].x);
            acc1[b].y = fmaf(xc.x, wi1, acc1[b].y); acc1[b].y = fmaf( xc.y, wr1, acc1[b].y);
        }
    }

    float2* out2 = (float2*)out;
    #pragma unroll
    for (int b = 0; b < BLPB; ++b) {
        long plane = (long)(bl0 + b) * OUT_CH;
        long d0 = (plane + o0)      * HW + (long)h * W_ + j;
        long d1 = (plane + o0 + 16) * HW + (long)h * W_ + j;
        out2[d0] = acc0[b];
        out2[d1] = acc1[b];
    }
}

extern "C" void kernel_launch(void* const* d_in, const int* in_sizes, int n_in,
                              void* d_out, int out_size, void* d_ws, size_t ws_size,
                              hipStream_t stream) {
    const float* x_re  = (const float*)d_in[0];
    const float* x_im  = (const float*)d_in[1];
    const float* w1_re = (const float*)d_in[2];
    const float* w1_im = (const float*)d_in[3];
    const float* w2_re = (const float*)d_in[4];
    const float* w2_im = (const float*)d_in[5];
    float* out = (float*)d_out;

    spectral_fused<<<dim3(2048), dim3(256), 0, stream>>>(
        x_re, x_im, w1_re, w1_im, w2_re, w2_im, out);
}

// Round 4
// 37.137 us; speedup vs baseline: 1.3703x; 1.0187x over previous
//
#include <hip/hip_runtime.h>

#define IN_CH 32
#define OUT_CH 32
#define M1 16
#define M2 16
#define H_ 64
#define W_ 33
#define HW (H_*W_)          // 2112
#define BLPB 4              // batch-l elements per compute block
#define WSTRIDE (OUT_CH*M1*M2)  // 8192 floats per c step in w
#define CBATCH 8            // weight loads batched 8 c-steps deep (32 dwords in flight)

// Single kernel, 2048 blocks x 256 threads.
//   even blocks (1024): compute the two mode regions (BLPB bl per block)
//   odd blocks  (1024): zero-fill the complement (pure write stream)
__global__ __launch_bounds__(256) void spectral_fused(
    const float* __restrict__ x_re, const float* __restrict__ x_im,
    const float* __restrict__ w1_re, const float* __restrict__ w1_im,
    const float* __restrict__ w2_re, const float* __restrict__ w2_im,
    float* __restrict__ out)
{
    const int tid = threadIdx.x;

    if (blockIdx.x & 1) {
        // ---------------- fill role ----------------
        const int fid = blockIdx.x >> 1;          // [0, 1024)
        const int gtid = fid * 256 + tid;
        const int nthreads = 1024 * 256;

        float4* out4 = (float4*)out;
        const float4 z4 = make_float4(0.f, 0.f, 0.f, 0.f);
        const int totalA = 4096 * 528;
        for (int idx = gtid; idx < totalA; idx += nthreads) {
            int plane = idx / 528;
            int k = idx - plane * 528;
            out4[(long)plane * 1056 + 264 + k] = z4;
        }
        float2* out2 = (float2*)out;
        const float2 z2 = make_float2(0.f, 0.f);
        const int totalB = 4096 * 544;
        for (int idx = gtid; idx < totalB; idx += nthreads) {
            int plane = idx / 544;
            int r = idx - plane * 544;
            int hh = r / 17;
            int t = r - hh * 17;
            int h = hh < 16 ? hh : hh + 32;
            out2[(long)plane * 2112 + h * 33 + 16 + t] = z2;
        }
        return;
    }

    // ---------------- compute role ----------------
    const int cid = blockIdx.x >> 1;      // [0, 1024)
    const int ri = cid >> 5;              // region*16 + i
    const int chunk = cid & 31;           // 32 chunks of BLPB bl
    const int region = ri >> 4;
    const int i = ri & 15;
    const int h = region ? (48 + i) : i;
    const int bl0 = chunk * BLPB;

    __shared__ float2 xs[BLPB][IN_CH][M2];   // 16 KB

    for (int item = tid; item < BLPB * IN_CH * M2; item += 256) {
        int j = item & 15;
        int c = (item >> 4) & 31;
        int b = item >> 9;
        long src = (long)((bl0 + b) * IN_CH + c) * HW + (long)h * W_ + j;
        xs[b][c][j] = make_float2(x_re[src], x_im[src]);
    }
    __syncthreads();

    const int j  = tid & 15;
    const int o0 = tid >> 4;              // [0,16); also handles o0+16
    const float* __restrict__ wre = (region ? w2_re : w1_re) + (o0 * M1 + i) * M2 + j;
    const float* __restrict__ wim = (region ? w2_im : w1_im) + (o0 * M1 + i) * M2 + j;

    float2 acc0[BLPB], acc1[BLPB];
    #pragma unroll
    for (int b = 0; b < BLPB; ++b) {
        acc0[b] = make_float2(0.f, 0.f);
        acc1[b] = make_float2(0.f, 0.f);
    }

    // Batched c-loop: issue 32 independent weight loads (8 KB/wave in flight),
    // then consume. Explicit arrays with full unroll -> compile-time indexing.
    #pragma unroll 1
    for (int cb = 0; cb < IN_CH; cb += CBATCH) {
        float wr0[CBATCH], wi0[CBATCH], wr1[CBATCH], wi1[CBATCH];
        #pragma unroll
        for (int u = 0; u < CBATCH; ++u) {
            int idx = (cb + u) * WSTRIDE;
            wr0[u] = wre[idx];        wi0[u] = wim[idx];
            wr1[u] = wre[idx + 4096]; wi1[u] = wim[idx + 4096];
        }
        #pragma unroll
        for (int u = 0; u < CBATCH; ++u) {
            #pragma unroll
            for (int b = 0; b < BLPB; ++b) {
                float2 xc = xs[b][cb + u][j];
                acc0[b].x = fmaf(xc.x, wr0[u], acc0[b].x); acc0[b].x = fmaf(-xc.y, wi0[u], acc0[b].x);
                acc0[b].y = fmaf(xc.x, wi0[u], acc0[b].y); acc0[b].y = fmaf( xc.y, wr0[u], acc0[b].y);
                acc1[b].x = fmaf(xc.x, wr1[u], acc1[b].x); acc1[b].x = fmaf(-xc.y, wi1[u], acc1[b].x);
                acc1[b].y = fmaf(xc.x, wi1[u], acc1[b].y); acc1[b].y = fmaf( xc.y, wr1[u], acc1[b].y);
            }
        }
    }

    float2* out2 = (float2*)out;
    #pragma unroll
    for (int b = 0; b < BLPB; ++b) {
        long plane = (long)(bl0 + b) * OUT_CH;
        long d0 = (plane + o0)      * HW + (long)h * W_ + j;
        long d1 = (plane + o0 + 16) * HW + (long)h * W_ + j;
        out2[d0] = acc0[b];
        out2[d1] = acc1[b];
    }
}

extern "C" void kernel_launch(void* const* d_in, const int* in_sizes, int n_in,
                              void* d_out, int out_size, void* d_ws, size_t ws_size,
                              hipStream_t stream) {
    const float* x_re  = (const float*)d_in[0];
    const float* x_im  = (const float*)d_in[1];
    const float* w1_re = (const float*)d_in[2];
    const float* w1_im = (const float*)d_in[3];
    const float* w2_re = (const float*)d_in[4];
    const float* w2_im = (const float*)d_in[5];
    float* out = (float*)d_out;

    spectral_fused<<<dim3(2048), dim3(256), 0, stream>>>(
        x_re, x_im, w1_re, w1_im, w2_re, w2_im, out);
}